// Round 1
// baseline (1435.610 us; speedup 1.0000x reference)
//
#include <hip/hip_runtime.h>
#include <hip/hip_bf16.h>

// ---------------------------------------------------------------------------
// GCN: h1 = relu(gcnconv(x, W1, b1)); h2 = relu(gcnconv(h1, W2, b2));
//      out = h2 @ Wh + bh
// gcnconv(x,W,b)[d] = dinv[d] * ( sum_{e: src->d} hs[src] + hs[d] ) + b
//   where hs = (x@W) * dinv[row],  dinv = rsqrt(indeg + 1)
// ---------------------------------------------------------------------------

__device__ __forceinline__ void atomic_add_f32(float* p, float v) {
  asm volatile("global_atomic_add_f32 %0, %1, off" :: "v"(p), "v"(v) : "memory");
}

__global__ __launch_bounds__(256) void k_init_deg(int* deg, int n) {
  int i = blockIdx.x * blockDim.x + threadIdx.x;
  if (i < n) deg[i] = 1;  // self-loop
}

__global__ __launch_bounds__(256) void k_count(const int* __restrict__ dst, int* deg, int E) {
  int e = blockIdx.x * blockDim.x + threadIdx.x;
  if (e < E) atomicAdd(&deg[dst[e]], 1);
}

__global__ __launch_bounds__(256) void k_dinv(const int* __restrict__ deg, float* dinv, int n) {
  int i = blockIdx.x * blockDim.x + threadIdx.x;
  if (i < n) dinv[i] = rsqrtf((float)deg[i]);
}

// Y[row][j] = (sum_k X[row][k] * W[k][j]) [*dinv[row]] [+bias[j]]
// Block: 256 threads = 4 waves, each wave computes 4 rows x NOUT cols.
template<int K, int NOUT, bool SCALE, bool BIAS>
__global__ __launch_bounds__(256) void k_gemm(
    const float* X, const float* __restrict__ W, const float* __restrict__ dinv,
    const float* __restrict__ bias, float* Y, int nrows)
{
  constexpr int LDW = K + 4;             // pad 4 floats: b128 reads conflict-free
  __shared__ float WT[NOUT * LDW];
  for (int idx = threadIdx.x; idx < K * NOUT; idx += 256) {
    int k = idx / NOUT, j = idx - k * NOUT;
    WT[j * LDW + k] = W[idx];
  }
  __syncthreads();

  const int wid = threadIdx.x >> 6;
  const int lane = threadIdx.x & 63;
  const int jj = (NOUT < 64 && lane >= NOUT) ? 0 : lane;   // clamp for LDS safety
  const float* wrow = &WT[jj * LDW];

  const int r0 = (blockIdx.x * 4 + wid) * 4;
  float acc0 = 0.f, acc1 = 0.f, acc2 = 0.f, acc3 = 0.f;
  const float* xr0; const float* xr1; const float* xr2; const float* xr3;
  {
    int a = r0 + 0; if (a >= nrows) a = nrows - 1;
    int b = r0 + 1; if (b >= nrows) b = nrows - 1;
    int c = r0 + 2; if (c >= nrows) c = nrows - 1;
    int d = r0 + 3; if (d >= nrows) d = nrows - 1;
    xr0 = X + (size_t)a * K; xr1 = X + (size_t)b * K;
    xr2 = X + (size_t)c * K; xr3 = X + (size_t)d * K;
  }

  #pragma unroll
  for (int k = 0; k < K; k += 4) {
    float4 wv = *(const float4*)(wrow + k);
    float4 x0 = *(const float4*)(xr0 + k);   // same addr across lanes: L1 broadcast
    float4 x1 = *(const float4*)(xr1 + k);
    float4 x2 = *(const float4*)(xr2 + k);
    float4 x3 = *(const float4*)(xr3 + k);
    acc0 = fmaf(x0.x, wv.x, acc0); acc0 = fmaf(x0.y, wv.y, acc0);
    acc0 = fmaf(x0.z, wv.z, acc0); acc0 = fmaf(x0.w, wv.w, acc0);
    acc1 = fmaf(x1.x, wv.x, acc1); acc1 = fmaf(x1.y, wv.y, acc1);
    acc1 = fmaf(x1.z, wv.z, acc1); acc1 = fmaf(x1.w, wv.w, acc1);
    acc2 = fmaf(x2.x, wv.x, acc2); acc2 = fmaf(x2.y, wv.y, acc2);
    acc2 = fmaf(x2.z, wv.z, acc2); acc2 = fmaf(x2.w, wv.w, acc2);
    acc3 = fmaf(x3.x, wv.x, acc3); acc3 = fmaf(x3.y, wv.y, acc3);
    acc3 = fmaf(x3.z, wv.z, acc3); acc3 = fmaf(x3.w, wv.w, acc3);
  }

  float accs[4] = {acc0, acc1, acc2, acc3};
  #pragma unroll
  for (int r = 0; r < 4; ++r) {
    int row = r0 + r;
    if (row < nrows && lane < NOUT) {
      float v = accs[r];
      if constexpr (SCALE) v *= dinv[row];
      if constexpr (BIAS)  v += bias[lane];
      Y[(size_t)row * NOUT + lane] = v;
    }
  }
}

// B[dst[e]][lane] += A[src[e]][lane]  (64 features per row), 1 wave per edge,
// 4 edges per wave for ILP.
__global__ __launch_bounds__(256) void k_agg(
    const float* __restrict__ A, float* B,
    const int* __restrict__ src, const int* __restrict__ dst, int E)
{
  int gwid = (blockIdx.x * 256 + threadIdx.x) >> 6;
  int lane = threadIdx.x & 63;
  int e0 = gwid * 4;
  #pragma unroll
  for (int i = 0; i < 4; ++i) {
    int e = e0 + i;
    if (e < E) {
      int s = src[e];
      int d = dst[e];
      float v = A[(size_t)s * 64 + lane];
      atomic_add_f32(&B[(size_t)d * 64 + lane], v);
    }
  }
  asm volatile("s_waitcnt vmcnt(0)" ::: "memory");
}

// inout = relu(dinv[row] * (other + inout) + bias[col])   (float4 over N x 64)
__global__ __launch_bounds__(256) void k_post(
    const float* __restrict__ other, float* inout,
    const float* __restrict__ dinv, const float* __restrict__ bias, int n)
{
  int idx = blockIdx.x * blockDim.x + threadIdx.x;   // float4 index, 16 per row
  if (idx >= n * 16) return;
  int row = idx >> 4;
  int c4 = idx & 15;
  float d = dinv[row];
  float4 a = ((const float4*)other)[idx];
  float4 b = ((float4*)inout)[idx];
  float4 bb = ((const float4*)bias)[c4];
  float4 o;
  o.x = fmaxf(fmaf(d, a.x + b.x, bb.x), 0.f);
  o.y = fmaxf(fmaf(d, a.y + b.y, bb.y), 0.f);
  o.z = fmaxf(fmaf(d, a.z + b.z, bb.z), 0.f);
  o.w = fmaxf(fmaf(d, a.w + b.w, bb.w), 0.f);
  ((float4*)inout)[idx] = o;
}

extern "C" void kernel_launch(void* const* d_in, const int* in_sizes, int n_in,
                              void* d_out, int out_size, void* d_ws, size_t ws_size,
                              hipStream_t stream) {
  const float* x  = (const float*)d_in[0];
  const int*   ei = (const int*)d_in[1];
  const float* W1 = (const float*)d_in[2];
  const float* b1 = (const float*)d_in[3];
  const float* W2 = (const float*)d_in[4];
  const float* b2 = (const float*)d_in[5];
  const float* Wh = (const float*)d_in[6];
  const float* bh = (const float*)d_in[7];
  float* out = (float*)d_out;

  const int N = in_sizes[0] / 128;
  const int E = in_sizes[1] / 2;
  const int* src = ei;
  const int* dst = ei + E;

  auto align_up = [](size_t v, size_t a) { return (v + a - 1) & ~(a - 1); };
  char* ws = (char*)d_ws;
  size_t off = 0;
  int* deg = (int*)(ws + off);   off = align_up(off + (size_t)N * 4, 256);
  float* dinv = (float*)(ws + off); off = align_up(off + (size_t)N * 4, 256);
  float* A = (float*)(ws + off); off = align_up(off + (size_t)N * 64 * 4, 256);
  float* B = (float*)(ws + off); off = align_up(off + (size_t)N * 64 * 4, 256);
  (void)ws_size;

  const int TB = 256;
  const int gN = (N + TB - 1) / TB;
  const int gE = (E + TB - 1) / TB;
  const int gGemm = (N + 15) / 16;              // 16 rows per block
  const int gAgg = (((E + 3) / 4) + 3) / 4;     // 1 wave per 4 edges, 4 waves/block
  const int gPost = ((N * 16) + TB - 1) / TB;

  // degrees and dinv
  k_init_deg<<<gN, TB, 0, stream>>>(deg, N);
  k_count<<<gE, TB, 0, stream>>>(dst, deg, E);
  k_dinv<<<gN, TB, 0, stream>>>(deg, dinv, N);

  // ---- layer 1 ----
  k_gemm<128, 64, true, false><<<gGemm, TB, 0, stream>>>(x, W1, dinv, nullptr, A, N);
  hipMemsetAsync(B, 0, (size_t)N * 64 * 4, stream);
  k_agg<<<gAgg, TB, 0, stream>>>(A, B, src, dst, E);
  k_post<<<gPost, TB, 0, stream>>>(A, B, dinv, b1, N);   // B = h2 input

  // ---- layer 2 ----
  k_gemm<64, 64, true, false><<<gGemm, TB, 0, stream>>>(B, W2, dinv, nullptr, B, N); // in-place ok: row-exclusive
  hipMemsetAsync(A, 0, (size_t)N * 64 * 4, stream);
  k_agg<<<gAgg, TB, 0, stream>>>(B, A, src, dst, E);
  k_post<<<gPost, TB, 0, stream>>>(B, A, dinv, b2, N);   // A = h3

  // ---- head ----
  k_gemm<64, 40, false, true><<<gGemm, TB, 0, stream>>>(A, Wh, nullptr, bh, out, N);
}

// Round 2
// 1068.291 us; speedup vs baseline: 1.3438x; 1.3438x over previous
//
#include <hip/hip_runtime.h>
#include <hip/hip_bf16.h>

// ---------------------------------------------------------------------------
// GCN: h1 = relu(gcnconv(x, W1, b1)); h2 = relu(gcnconv(h1, W2, b2));
//      out = h2 @ Wh + bh
// gcnconv(x,W,b)[d] = dinv[d] * ( sum_{e: src->d} hs[src] + hs[d] ) + b
//   where hs = (x@W) * dinv[row],  dinv = rsqrt(indeg + 1)
// ---------------------------------------------------------------------------

__device__ __forceinline__ void atomic_add_f32(float* p, float v) {
  asm volatile("global_atomic_add_f32 %0, %1, off" :: "v"(p), "v"(v) : "memory");
}

__global__ __launch_bounds__(256) void k_init_deg(int* deg, int n) {
  int i = blockIdx.x * blockDim.x + threadIdx.x;
  if (i < n) deg[i] = 1;  // self-loop
}

__global__ __launch_bounds__(256) void k_count(const int* __restrict__ dst, int* deg, int E) {
  int e = blockIdx.x * blockDim.x + threadIdx.x;
  if (e < E) atomicAdd(&deg[dst[e]], 1);
}

__global__ __launch_bounds__(256) void k_dinv(const int* __restrict__ deg, float* dinv, int n) {
  int i = blockIdx.x * blockDim.x + threadIdx.x;
  if (i < n) dinv[i] = rsqrtf((float)deg[i]);
}

// Y[row][j] = (sum_k X[row][k] * W[k][j]) [*dinv[row]] [+bias[j]]
// Block: 256 threads = 4 waves. W staged in LDS row-major (scalar reads,
// 2-way bank aliasing = free). Each wave: 2 rows concurrently (2 FMA chains),
// RPW rows sequentially. x-row loads are same-address float4 -> L1 broadcast.
template<int K, int NOUT, int RPW, bool SCALE, bool BIAS>
__global__ __launch_bounds__(256) void k_gemm(
    const float* __restrict__ X, const float* __restrict__ W,
    const float* __restrict__ dinv, const float* __restrict__ bias,
    float* __restrict__ Y, int nrows)
{
  __shared__ float Ws[K * NOUT];
  for (int idx = threadIdx.x; idx < K * NOUT; idx += 256)
    Ws[idx] = W[idx];
  __syncthreads();

  const int wid  = threadIdx.x >> 6;
  const int lane = threadIdx.x & 63;
  const int j    = (NOUT < 64 && lane >= NOUT) ? (NOUT - 1) : lane;
  const float bj = BIAS ? bias[j] : 0.f;

  const int rowbase = (blockIdx.x * 4 + wid) * RPW;

  #pragma unroll 1
  for (int rr = 0; rr < RPW; rr += 2) {
    const int r0 = rowbase + rr;
    const int r1 = rowbase + rr + 1;
    const int c0 = (r0 < nrows) ? r0 : (nrows - 1);
    const int c1 = (r1 < nrows) ? r1 : (nrows - 1);
    const float* x0 = X + (size_t)c0 * K;
    const float* x1 = X + (size_t)c1 * K;
    float acc0 = 0.f, acc1 = 0.f;
    #pragma unroll
    for (int k = 0; k < K; k += 4) {
      const float4 a = *(const float4*)(x0 + k);
      const float4 b = *(const float4*)(x1 + k);
      const float w0 = Ws[(k + 0) * NOUT + j];
      const float w1 = Ws[(k + 1) * NOUT + j];
      const float w2 = Ws[(k + 2) * NOUT + j];
      const float w3 = Ws[(k + 3) * NOUT + j];
      acc0 = fmaf(a.x, w0, acc0); acc1 = fmaf(b.x, w0, acc1);
      acc0 = fmaf(a.y, w1, acc0); acc1 = fmaf(b.y, w1, acc1);
      acc0 = fmaf(a.z, w2, acc0); acc1 = fmaf(b.z, w2, acc1);
      acc0 = fmaf(a.w, w3, acc0); acc1 = fmaf(b.w, w3, acc1);
    }
    if (lane < NOUT) {
      if (r0 < nrows) {
        float v = acc0;
        if constexpr (SCALE) v *= dinv[r0];
        if constexpr (BIAS)  v += bj;
        Y[(size_t)r0 * NOUT + lane] = v;
      }
      if (r1 < nrows) {
        float v = acc1;
        if constexpr (SCALE) v *= dinv[r1];
        if constexpr (BIAS)  v += bj;
        Y[(size_t)r1 * NOUT + lane] = v;
      }
    }
  }
}

// B[dst[e]][lane] += A[src[e]][lane]  (64 features per row), 1 wave per edge,
// 4 edges per wave for ILP.
__global__ __launch_bounds__(256) void k_agg(
    const float* __restrict__ A, float* B,
    const int* __restrict__ src, const int* __restrict__ dst, int E)
{
  int gwid = (blockIdx.x * 256 + threadIdx.x) >> 6;
  int lane = threadIdx.x & 63;
  int e0 = gwid * 4;
  #pragma unroll
  for (int i = 0; i < 4; ++i) {
    int e = e0 + i;
    if (e < E) {
      int s = src[e];
      int d = dst[e];
      float v = A[(size_t)s * 64 + lane];
      atomic_add_f32(&B[(size_t)d * 64 + lane], v);
    }
  }
  asm volatile("s_waitcnt vmcnt(0)" ::: "memory");
}

// inout = relu(dinv[row] * (other + inout) + bias[col])   (float4 over N x 64)
__global__ __launch_bounds__(256) void k_post(
    const float* __restrict__ other, float* inout,
    const float* __restrict__ dinv, const float* __restrict__ bias, int n)
{
  int idx = blockIdx.x * blockDim.x + threadIdx.x;   // float4 index, 16 per row
  if (idx >= n * 16) return;
  int row = idx >> 4;
  int c4 = idx & 15;
  float d = dinv[row];
  float4 a = ((const float4*)other)[idx];
  float4 b = ((float4*)inout)[idx];
  float4 bb = ((const float4*)bias)[c4];
  float4 o;
  o.x = fmaxf(fmaf(d, a.x + b.x, bb.x), 0.f);
  o.y = fmaxf(fmaf(d, a.y + b.y, bb.y), 0.f);
  o.z = fmaxf(fmaf(d, a.z + b.z, bb.z), 0.f);
  o.w = fmaxf(fmaf(d, a.w + b.w, bb.w), 0.f);
  ((float4*)inout)[idx] = o;
}

extern "C" void kernel_launch(void* const* d_in, const int* in_sizes, int n_in,
                              void* d_out, int out_size, void* d_ws, size_t ws_size,
                              hipStream_t stream) {
  const float* x  = (const float*)d_in[0];
  const int*   ei = (const int*)d_in[1];
  const float* W1 = (const float*)d_in[2];
  const float* b1 = (const float*)d_in[3];
  const float* W2 = (const float*)d_in[4];
  const float* b2 = (const float*)d_in[5];
  const float* Wh = (const float*)d_in[6];
  const float* bh = (const float*)d_in[7];
  float* out = (float*)d_out;

  const int N = in_sizes[0] / 128;
  const int E = in_sizes[1] / 2;
  const int* src = ei;
  const int* dst = ei + E;

  auto align_up = [](size_t v, size_t a) { return (v + a - 1) & ~(a - 1); };
  char* ws = (char*)d_ws;
  size_t off = 0;
  int* deg = (int*)(ws + off);   off = align_up(off + (size_t)N * 4, 256);
  float* dinv = (float*)(ws + off); off = align_up(off + (size_t)N * 4, 256);
  float* A = (float*)(ws + off); off = align_up(off + (size_t)N * 64 * 4, 256);
  float* B = (float*)(ws + off); off = align_up(off + (size_t)N * 64 * 4, 256);
  (void)ws_size;

  const int TB = 256;
  const int gN = (N + TB - 1) / TB;
  const int gE = (E + TB - 1) / TB;
  constexpr int RPW = 8;                        // rows per wave (sequential)
  const int gGemm = (N + 4 * RPW - 1) / (4 * RPW);
  const int gAgg = (((E + 3) / 4) + 3) / 4;     // 1 wave per 4 edges, 4 waves/block
  const int gPost = ((N * 16) + TB - 1) / TB;

  // degrees and dinv
  k_init_deg<<<gN, TB, 0, stream>>>(deg, N);
  k_count<<<gE, TB, 0, stream>>>(dst, deg, E);
  k_dinv<<<gN, TB, 0, stream>>>(deg, dinv, N);

  // ---- layer 1 ----  A = hs1 = (x@W1)*dinv
  k_gemm<128, 64, RPW, true, false><<<gGemm, TB, 0, stream>>>(x, W1, dinv, nullptr, A, N);
  hipMemsetAsync(B, 0, (size_t)N * 64 * 4, stream);
  k_agg<<<gAgg, TB, 0, stream>>>(A, B, src, dst, E);
  k_post<<<gPost, TB, 0, stream>>>(A, B, dinv, b1, N);   // B = h1

  // ---- layer 2 ----  A = hs2 = (h1@W2)*dinv   (B read, A written: no aliasing)
  k_gemm<64, 64, RPW, true, false><<<gGemm, TB, 0, stream>>>(B, W2, dinv, nullptr, A, N);
  hipMemsetAsync(B, 0, (size_t)N * 64 * 4, stream);
  k_agg<<<gAgg, TB, 0, stream>>>(A, B, src, dst, E);
  k_post<<<gPost, TB, 0, stream>>>(A, B, dinv, b2, N);   // B = h2

  // ---- head ----  out = h2 @ Wh + bh
  k_gemm<64, 40, RPW, false, true><<<gGemm, TB, 0, stream>>>(B, Wh, nullptr, bh, out, N);
}

// Round 3
// 610.231 us; speedup vs baseline: 2.3526x; 1.7506x over previous
//
#include <hip/hip_runtime.h>
#include <hip/hip_bf16.h>

// ---------------------------------------------------------------------------
// GCN: h1 = relu(gcnconv(x, W1, b1)); h2 = relu(gcnconv(h1, W2, b2));
//      out = h2 @ Wh + bh
// gcnconv(x,W,b)[d] = dinv[d] * ( sum_{e: src->d} hs[src] + hs[d] ) + b
//   where hs = (x@W) * dinv[row],  dinv = rsqrt(indeg + 1)
// Aggregation = CSR pull (no fp32 atomics): CSR built per call via
// count -> 3-pass scan -> scatter (int atomics for within-bucket slots).
// ---------------------------------------------------------------------------

__global__ __launch_bounds__(256) void k_zero(int* p, int n) {
  int i = blockIdx.x * blockDim.x + threadIdx.x;
  if (i < n) p[i] = 0;
}

__global__ __launch_bounds__(256) void k_count(const int* __restrict__ dst, int* cnt, int E) {
  int e = blockIdx.x * blockDim.x + threadIdx.x;
  if (e < E) atomicAdd(&cnt[dst[e]], 1);
}

__global__ __launch_bounds__(256) void k_dinv(const int* __restrict__ cnt, float* dinv, int n) {
  int i = blockIdx.x * blockDim.x + threadIdx.x;
  if (i < n) dinv[i] = rsqrtf((float)(cnt[i] + 1));   // +1 self-loop
}

// ---- 3-pass exclusive scan of cnt[n] -> offs[n]; bsum has >= ceil(n/1024) ints
__global__ __launch_bounds__(256) void k_scan1(const int* __restrict__ cnt,
                                               int* offs, int* bsum, int n) {
  __shared__ int sh[256];
  const int t = threadIdx.x;
  const int base = blockIdx.x * 1024 + t * 4;
  int v0 = 0, v1 = 0, v2 = 0, v3 = 0;
  if (base + 0 < n) v0 = cnt[base + 0];
  if (base + 1 < n) v1 = cnt[base + 1];
  if (base + 2 < n) v2 = cnt[base + 2];
  if (base + 3 < n) v3 = cnt[base + 3];
  const int s = v0 + v1 + v2 + v3;
  sh[t] = s;
  __syncthreads();
  for (int d = 1; d < 256; d <<= 1) {
    int x = (t >= d) ? sh[t - d] : 0;
    __syncthreads();
    sh[t] += x;
    __syncthreads();
  }
  int o = sh[t] - s;                       // exclusive prefix of this thread's chunk
  if (t == 255) bsum[blockIdx.x] = sh[255];
  if (base + 0 < n) { offs[base + 0] = o; o += v0; }
  if (base + 1 < n) { offs[base + 1] = o; o += v1; }
  if (base + 2 < n) { offs[base + 2] = o; o += v2; }
  if (base + 3 < n) { offs[base + 3] = o; o += v3; }
}

__global__ __launch_bounds__(256) void k_scan2(int* bsum, int nb) {
  __shared__ int sh[256];
  const int t = threadIdx.x;
  int v = (t < nb) ? bsum[t] : 0;
  sh[t] = v;
  __syncthreads();
  for (int d = 1; d < 256; d <<= 1) {
    int x = (t >= d) ? sh[t - d] : 0;
    __syncthreads();
    sh[t] += x;
    __syncthreads();
  }
  if (t < nb) bsum[t] = sh[t] - v;         // exclusive
}

__global__ __launch_bounds__(256) void k_scan3(int* offs, const int* __restrict__ bsum,
                                               int* cursor, int n) {
  int i = blockIdx.x * blockDim.x + threadIdx.x;
  if (i < n) {
    int o = offs[i] + bsum[i >> 10];
    offs[i] = o;
    cursor[i] = o;
  }
}

__global__ __launch_bounds__(256) void k_fill(const int* __restrict__ src,
                                              const int* __restrict__ dst,
                                              int* cursor, int* csr, int E) {
  int e = blockIdx.x * blockDim.x + threadIdx.x;
  if (e < E) {
    int p = atomicAdd(&cursor[dst[e]], 1);
    csr[p] = src[e];
  }
}

// Y[row][j] = (sum_k X[row][k] * W[k][j]) [*dinv[row]] [+bias[j]]
// Block: 256 threads = 4 waves. W staged in LDS row-major.
template<int K, int NOUT, int RPW, bool SCALE, bool BIAS>
__global__ __launch_bounds__(256) void k_gemm(
    const float* __restrict__ X, const float* __restrict__ W,
    const float* __restrict__ dinv, const float* __restrict__ bias,
    float* __restrict__ Y, int nrows)
{
  __shared__ float Ws[K * NOUT];
  for (int idx = threadIdx.x; idx < K * NOUT; idx += 256)
    Ws[idx] = W[idx];
  __syncthreads();

  const int wid  = threadIdx.x >> 6;
  const int lane = threadIdx.x & 63;
  const int j    = (NOUT < 64 && lane >= NOUT) ? (NOUT - 1) : lane;
  const float bj = BIAS ? bias[j] : 0.f;

  const int rowbase = (blockIdx.x * 4 + wid) * RPW;

  #pragma unroll 1
  for (int rr = 0; rr < RPW; rr += 2) {
    const int r0 = rowbase + rr;
    const int r1 = rowbase + rr + 1;
    const int c0 = (r0 < nrows) ? r0 : (nrows - 1);
    const int c1 = (r1 < nrows) ? r1 : (nrows - 1);
    const float* x0 = X + (size_t)c0 * K;
    const float* x1 = X + (size_t)c1 * K;
    float acc0 = 0.f, acc1 = 0.f;
    #pragma unroll
    for (int k = 0; k < K; k += 4) {
      const float4 a = *(const float4*)(x0 + k);
      const float4 b = *(const float4*)(x1 + k);
      const float w0 = Ws[(k + 0) * NOUT + j];
      const float w1 = Ws[(k + 1) * NOUT + j];
      const float w2 = Ws[(k + 2) * NOUT + j];
      const float w3 = Ws[(k + 3) * NOUT + j];
      acc0 = fmaf(a.x, w0, acc0); acc1 = fmaf(b.x, w0, acc1);
      acc0 = fmaf(a.y, w1, acc0); acc1 = fmaf(b.y, w1, acc1);
      acc0 = fmaf(a.z, w2, acc0); acc1 = fmaf(b.z, w2, acc1);
      acc0 = fmaf(a.w, w3, acc0); acc1 = fmaf(b.w, w3, acc1);
    }
    if (lane < NOUT) {
      if (r0 < nrows) {
        float v = acc0;
        if constexpr (SCALE) v *= dinv[r0];
        if constexpr (BIAS)  v += bj;
        Y[(size_t)r0 * NOUT + lane] = v;
      }
      if (r1 < nrows) {
        float v = acc1;
        if constexpr (SCALE) v *= dinv[r1];
        if constexpr (BIAS)  v += bj;
        Y[(size_t)r1 * NOUT + lane] = v;
      }
    }
  }
}

// Pull-aggregate + fused epilogue. One wave per node, lane = feature.
// out[node][lane] = relu(dinv[node] * (hs[node][lane] + sum_in hs[src][lane]) + bias[lane])
__global__ __launch_bounds__(256) void k_pull(
    const float* __restrict__ hs, const int* __restrict__ csr,
    const int* __restrict__ offs, const int* __restrict__ endo,
    const float* __restrict__ dinv, const float* __restrict__ bias,
    float* __restrict__ out, int n)
{
  const int node = blockIdx.x * 4 + (threadIdx.x >> 6);
  if (node >= n) return;
  const int lane = threadIdx.x & 63;

  const int beg = offs[node];
  const int m   = endo[node] - beg;        // endo = cursor after fill = end offset

  float acc0 = hs[(size_t)node * 64 + lane];   // self term
  float acc1 = 0.f;

  for (int base = 0; base < m; base += 64) {
    const int kk = (m - base < 64) ? (m - base) : 64;
    const int myidx = (base + lane < m) ? csr[beg + base + lane] : 0;
    int i = 0;
    for (; i + 4 <= kk; i += 4) {
      int s0 = __shfl(myidx, i + 0);
      int s1 = __shfl(myidx, i + 1);
      int s2 = __shfl(myidx, i + 2);
      int s3 = __shfl(myidx, i + 3);
      float a0 = hs[(size_t)s0 * 64 + lane];
      float a1 = hs[(size_t)s1 * 64 + lane];
      float a2 = hs[(size_t)s2 * 64 + lane];
      float a3 = hs[(size_t)s3 * 64 + lane];
      acc0 += a0; acc1 += a1; acc0 += a2; acc1 += a3;
    }
    for (; i < kk; ++i) {
      int s = __shfl(myidx, i);
      acc0 += hs[(size_t)s * 64 + lane];
    }
  }
  float v = fmaf(dinv[node], acc0 + acc1, bias[lane]);
  out[(size_t)node * 64 + lane] = fmaxf(v, 0.f);
}

extern "C" void kernel_launch(void* const* d_in, const int* in_sizes, int n_in,
                              void* d_out, int out_size, void* d_ws, size_t ws_size,
                              hipStream_t stream) {
  const float* x  = (const float*)d_in[0];
  const int*   ei = (const int*)d_in[1];
  const float* W1 = (const float*)d_in[2];
  const float* b1 = (const float*)d_in[3];
  const float* W2 = (const float*)d_in[4];
  const float* b2 = (const float*)d_in[5];
  const float* Wh = (const float*)d_in[6];
  const float* bh = (const float*)d_in[7];
  float* out = (float*)d_out;

  const int N = in_sizes[0] / 128;
  const int E = in_sizes[1] / 2;
  const int* src = ei;
  const int* dst = ei + E;

  auto align_up = [](size_t v, size_t a) { return (v + a - 1) & ~(a - 1); };
  char* ws = (char*)d_ws;
  size_t off = 0;
  int*   cnt    = (int*)(ws + off);   off = align_up(off + (size_t)N * 4, 256);
  float* dinv   = (float*)(ws + off); off = align_up(off + (size_t)N * 4, 256);
  int*   offs   = (int*)(ws + off);   off = align_up(off + (size_t)N * 4, 256);
  int*   cursor = (int*)(ws + off);   off = align_up(off + (size_t)N * 4, 256);
  int*   bsum   = (int*)(ws + off);   off = align_up(off + 256 * 4, 256);
  int*   csr    = (int*)(ws + off);   off = align_up(off + (size_t)E * 4, 256);
  float* A      = (float*)(ws + off); off = align_up(off + (size_t)N * 64 * 4, 256);
  float* B      = (float*)(ws + off); off = align_up(off + (size_t)N * 64 * 4, 256);
  (void)ws_size;

  const int TB = 256;
  const int gN = (N + TB - 1) / TB;
  const int gE = (E + TB - 1) / TB;
  const int nb = (N + 1023) / 1024;             // blocks in scan pass 1 (<=256)
  constexpr int RPW = 8;
  const int gGemm = (N + 4 * RPW - 1) / (4 * RPW);
  const int gPull = (N + 3) / 4;

  // ---- degree + CSR build ----
  k_zero <<<gN, TB, 0, stream>>>(cnt, N);
  k_count<<<gE, TB, 0, stream>>>(dst, cnt, E);
  k_dinv <<<gN, TB, 0, stream>>>(cnt, dinv, N);
  k_scan1<<<nb, TB, 0, stream>>>(cnt, offs, bsum, N);
  k_scan2<<<1,  TB, 0, stream>>>(bsum, nb);
  k_scan3<<<gN, TB, 0, stream>>>(offs, bsum, cursor, N);
  k_fill <<<gE, TB, 0, stream>>>(src, dst, cursor, csr, E);
  // after k_fill: cursor[i] == offs[i] + indeg(i)  (used as end-offsets)

  // ---- layer 1 ----  A = hs1 = (x@W1)*dinv ; B = h1
  k_gemm<128, 64, RPW, true, false><<<gGemm, TB, 0, stream>>>(x, W1, dinv, nullptr, A, N);
  k_pull<<<gPull, TB, 0, stream>>>(A, csr, offs, cursor, dinv, b1, B, N);

  // ---- layer 2 ----  A = hs2 = (h1@W2)*dinv ; B2 -> reuse: out into B via A
  k_gemm<64, 64, RPW, true, false><<<gGemm, TB, 0, stream>>>(B, W2, dinv, nullptr, A, N);
  k_pull<<<gPull, TB, 0, stream>>>(A, csr, offs, cursor, dinv, b2, B, N);

  // ---- head ----  out = h2 @ Wh + bh
  k_gemm<64, 40, RPW, false, true><<<gGemm, TB, 0, stream>>>(B, Wh, nullptr, bh, out, N);
}

// Round 4
// 446.944 us; speedup vs baseline: 3.2121x; 1.3653x over previous
//
#include <hip/hip_runtime.h>
#include <hip/hip_bf16.h>

// ---------------------------------------------------------------------------
// GCN: h1 = relu(gcnconv(x, W1, b1)); h2 = relu(gcnconv(h1, W2, b2));
//      out = h2 @ Wh + bh
// gcnconv(x,W,b)[d] = dinv[d] * ( sum_{e: src->d} hs[src] + hs[d] ) + b
//   where hs = (x@W) * dinv[row],  dinv = rsqrt(indeg + 1)
// Aggregation = CSR pull (no fp32 atomics). GEMM = WT-in-LDS (b128 reads,
// bank-even LDW=K+4), 4 uniform rows/wave via s_load (readfirstlane).
// ---------------------------------------------------------------------------

__global__ __launch_bounds__(256) void k_zero(int* p, int n) {
  int i = blockIdx.x * blockDim.x + threadIdx.x;
  if (i < n) p[i] = 0;
}

__global__ __launch_bounds__(256) void k_count(const int* __restrict__ dst, int* cnt, int E) {
  int e = blockIdx.x * blockDim.x + threadIdx.x;
  if (e < E) atomicAdd(&cnt[dst[e]], 1);
}

__global__ __launch_bounds__(256) void k_dinv(const int* __restrict__ cnt, float* dinv, int n) {
  int i = blockIdx.x * blockDim.x + threadIdx.x;
  if (i < n) dinv[i] = rsqrtf((float)(cnt[i] + 1));   // +1 self-loop
}

// ---- 3-pass exclusive scan of cnt[n] -> offs[n]
__global__ __launch_bounds__(256) void k_scan1(const int* __restrict__ cnt,
                                               int* offs, int* bsum, int n) {
  __shared__ int sh[256];
  const int t = threadIdx.x;
  const int base = blockIdx.x * 1024 + t * 4;
  int v0 = 0, v1 = 0, v2 = 0, v3 = 0;
  if (base + 0 < n) v0 = cnt[base + 0];
  if (base + 1 < n) v1 = cnt[base + 1];
  if (base + 2 < n) v2 = cnt[base + 2];
  if (base + 3 < n) v3 = cnt[base + 3];
  const int s = v0 + v1 + v2 + v3;
  sh[t] = s;
  __syncthreads();
  for (int d = 1; d < 256; d <<= 1) {
    int x = (t >= d) ? sh[t - d] : 0;
    __syncthreads();
    sh[t] += x;
    __syncthreads();
  }
  int o = sh[t] - s;
  if (t == 255) bsum[blockIdx.x] = sh[255];
  if (base + 0 < n) { offs[base + 0] = o; o += v0; }
  if (base + 1 < n) { offs[base + 1] = o; o += v1; }
  if (base + 2 < n) { offs[base + 2] = o; o += v2; }
  if (base + 3 < n) { offs[base + 3] = o; o += v3; }
}

__global__ __launch_bounds__(256) void k_scan2(int* bsum, int nb) {
  __shared__ int sh[256];
  const int t = threadIdx.x;
  int v = (t < nb) ? bsum[t] : 0;
  sh[t] = v;
  __syncthreads();
  for (int d = 1; d < 256; d <<= 1) {
    int x = (t >= d) ? sh[t - d] : 0;
    __syncthreads();
    sh[t] += x;
    __syncthreads();
  }
  if (t < nb) bsum[t] = sh[t] - v;
}

__global__ __launch_bounds__(256) void k_scan3(int* offs, const int* __restrict__ bsum,
                                               int* cursor, int n) {
  int i = blockIdx.x * blockDim.x + threadIdx.x;
  if (i < n) {
    int o = offs[i] + bsum[i >> 10];
    offs[i] = o;
    cursor[i] = o;
  }
}

__global__ __launch_bounds__(256) void k_fill(const int* __restrict__ src,
                                              const int* __restrict__ dst,
                                              int* cursor, int* csr, int E) {
  int e = blockIdx.x * blockDim.x + threadIdx.x;
  if (e < E) {
    int p = atomicAdd(&cursor[dst[e]], 1);
    csr[p] = src[e];
  }
}

// Y[row][j] = (sum_k X[row][k] * W[k][j]) [*dinv[row]] [+bias[j]]
// 256 threads = 4 waves; lane = output col j. WT in LDS [NOUT][K+4]:
// one ds_read_b128 per 16 FMAs, bank-even (LDW%32==4 -> 8 req/bank = min).
// 4 rows per wave concurrently; row addresses wave-uniform via readfirstlane
// -> x loads become s_load (scalar cache), freeing VMEM + VGPRs.
template<int K, int NOUT, int RPW, bool SCALE, bool BIAS>
__global__ __launch_bounds__(256) void k_gemm(
    const float* __restrict__ X, const float* __restrict__ W,
    const float* __restrict__ dinv, const float* __restrict__ bias,
    float* __restrict__ Y, int nrows)
{
  constexpr int LDW = K + 4;
  __shared__ float WT[NOUT * LDW];
  for (int idx = threadIdx.x; idx < K * NOUT; idx += 256) {
    int k = idx / NOUT, j = idx - k * NOUT;
    WT[j * LDW + k] = W[idx];
  }
  __syncthreads();

  const int wid  = threadIdx.x >> 6;
  const int lane = threadIdx.x & 63;
  const int j    = (NOUT < 64 && lane >= NOUT) ? (NOUT - 1) : lane;
  const float bj = BIAS ? bias[j] : 0.f;
  const float* wrow = &WT[j * LDW];

  const int rowbase = (blockIdx.x * 4 + wid) * RPW;

  #pragma unroll 1
  for (int rr = 0; rr < RPW; rr += 4) {
    const int r0 = rowbase + rr;
    int c0 = (r0 + 0 < nrows) ? r0 + 0 : nrows - 1;
    int c1 = (r0 + 1 < nrows) ? r0 + 1 : nrows - 1;
    int c2 = (r0 + 2 < nrows) ? r0 + 2 : nrows - 1;
    int c3 = (r0 + 3 < nrows) ? r0 + 3 : nrows - 1;
    c0 = __builtin_amdgcn_readfirstlane(c0);
    c1 = __builtin_amdgcn_readfirstlane(c1);
    c2 = __builtin_amdgcn_readfirstlane(c2);
    c3 = __builtin_amdgcn_readfirstlane(c3);
    const float* x0 = X + (size_t)c0 * K;
    const float* x1 = X + (size_t)c1 * K;
    const float* x2 = X + (size_t)c2 * K;
    const float* x3 = X + (size_t)c3 * K;

    float a0 = 0.f, a1 = 0.f, a2 = 0.f, a3 = 0.f;
    #pragma unroll 4
    for (int k = 0; k < K; k += 4) {
      const float4 wv = *(const float4*)(wrow + k);
      const float4 p0 = *(const float4*)(x0 + k);
      const float4 p1 = *(const float4*)(x1 + k);
      const float4 p2 = *(const float4*)(x2 + k);
      const float4 p3 = *(const float4*)(x3 + k);
      a0 = fmaf(p0.x, wv.x, a0); a0 = fmaf(p0.y, wv.y, a0);
      a0 = fmaf(p0.z, wv.z, a0); a0 = fmaf(p0.w, wv.w, a0);
      a1 = fmaf(p1.x, wv.x, a1); a1 = fmaf(p1.y, wv.y, a1);
      a1 = fmaf(p1.z, wv.z, a1); a1 = fmaf(p1.w, wv.w, a1);
      a2 = fmaf(p2.x, wv.x, a2); a2 = fmaf(p2.y, wv.y, a2);
      a2 = fmaf(p2.z, wv.z, a2); a2 = fmaf(p2.w, wv.w, a2);
      a3 = fmaf(p3.x, wv.x, a3); a3 = fmaf(p3.y, wv.y, a3);
      a3 = fmaf(p3.z, wv.z, a3); a3 = fmaf(p3.w, wv.w, a3);
    }

    float accs[4] = {a0, a1, a2, a3};
    #pragma unroll
    for (int r = 0; r < 4; ++r) {
      const int row = r0 + r;
      if (row < nrows && lane < NOUT) {
        float v = accs[r];
        if constexpr (SCALE) v *= dinv[row];
        if constexpr (BIAS)  v += bj;
        Y[(size_t)row * NOUT + lane] = v;
      }
    }
  }
}

// Pull-aggregate + fused epilogue. One wave per node, lane = feature.
__global__ __launch_bounds__(256) void k_pull(
    const float* __restrict__ hs, const int* __restrict__ csr,
    const int* __restrict__ offs, const int* __restrict__ endo,
    const float* __restrict__ dinv, const float* __restrict__ bias,
    float* __restrict__ out, int n)
{
  const int node = blockIdx.x * 4 + (threadIdx.x >> 6);
  if (node >= n) return;
  const int lane = threadIdx.x & 63;

  const int beg = offs[node];
  const int m   = endo[node] - beg;

  float acc0 = hs[(size_t)node * 64 + lane];   // self term
  float acc1 = 0.f;

  for (int base = 0; base < m; base += 64) {
    const int kk = (m - base < 64) ? (m - base) : 64;
    const int myidx = (base + lane < m) ? csr[beg + base + lane] : 0;
    int i = 0;
    for (; i + 4 <= kk; i += 4) {
      int s0 = __shfl(myidx, i + 0);
      int s1 = __shfl(myidx, i + 1);
      int s2 = __shfl(myidx, i + 2);
      int s3 = __shfl(myidx, i + 3);
      float v0 = hs[(size_t)s0 * 64 + lane];
      float v1 = hs[(size_t)s1 * 64 + lane];
      float v2 = hs[(size_t)s2 * 64 + lane];
      float v3 = hs[(size_t)s3 * 64 + lane];
      acc0 += v0; acc1 += v1; acc0 += v2; acc1 += v3;
    }
    for (; i < kk; ++i) {
      int s = __shfl(myidx, i);
      acc0 += hs[(size_t)s * 64 + lane];
    }
  }
  float v = fmaf(dinv[node], acc0 + acc1, bias[lane]);
  out[(size_t)node * 64 + lane] = fmaxf(v, 0.f);
}

extern "C" void kernel_launch(void* const* d_in, const int* in_sizes, int n_in,
                              void* d_out, int out_size, void* d_ws, size_t ws_size,
                              hipStream_t stream) {
  const float* x  = (const float*)d_in[0];
  const int*   ei = (const int*)d_in[1];
  const float* W1 = (const float*)d_in[2];
  const float* b1 = (const float*)d_in[3];
  const float* W2 = (const float*)d_in[4];
  const float* b2 = (const float*)d_in[5];
  const float* Wh = (const float*)d_in[6];
  const float* bh = (const float*)d_in[7];
  float* out = (float*)d_out;

  const int N = in_sizes[0] / 128;
  const int E = in_sizes[1] / 2;
  const int* src = ei;
  const int* dst = ei + E;

  auto align_up = [](size_t v, size_t a) { return (v + a - 1) & ~(a - 1); };
  char* ws = (char*)d_ws;
  size_t off = 0;
  int*   cnt    = (int*)(ws + off);   off = align_up(off + (size_t)N * 4, 256);
  float* dinv   = (float*)(ws + off); off = align_up(off + (size_t)N * 4, 256);
  int*   offs   = (int*)(ws + off);   off = align_up(off + (size_t)N * 4, 256);
  int*   cursor = (int*)(ws + off);   off = align_up(off + (size_t)N * 4, 256);
  int*   bsum   = (int*)(ws + off);   off = align_up(off + 256 * 4, 256);
  int*   csr    = (int*)(ws + off);   off = align_up(off + (size_t)E * 4, 256);
  float* A      = (float*)(ws + off); off = align_up(off + (size_t)N * 64 * 4, 256);
  float* B      = (float*)(ws + off); off = align_up(off + (size_t)N * 64 * 4, 256);
  (void)ws_size;

  const int TB = 256;
  const int gN = (N + TB - 1) / TB;
  const int gE = (E + TB - 1) / TB;
  const int nb = (N + 1023) / 1024;
  constexpr int RPW = 16;                        // rows per wave
  const int gGemm = (N + 4 * RPW - 1) / (4 * RPW);
  const int gPull = (N + 3) / 4;

  // ---- degree + CSR build ----
  k_zero <<<gN, TB, 0, stream>>>(cnt, N);
  k_count<<<gE, TB, 0, stream>>>(dst, cnt, E);
  k_dinv <<<gN, TB, 0, stream>>>(cnt, dinv, N);
  k_scan1<<<nb, TB, 0, stream>>>(cnt, offs, bsum, N);
  k_scan2<<<1,  TB, 0, stream>>>(bsum, nb);
  k_scan3<<<gN, TB, 0, stream>>>(offs, bsum, cursor, N);
  k_fill <<<gE, TB, 0, stream>>>(src, dst, cursor, csr, E);

  // ---- layer 1 ----  A = hs1 = (x@W1)*dinv ; B = h1
  k_gemm<128, 64, RPW, true, false><<<gGemm, TB, 0, stream>>>(x, W1, dinv, nullptr, A, N);
  k_pull<<<gPull, TB, 0, stream>>>(A, csr, offs, cursor, dinv, b1, B, N);

  // ---- layer 2 ----  A = hs2 = (h1@W2)*dinv ; B = h2
  k_gemm<64, 64, RPW, true, false><<<gGemm, TB, 0, stream>>>(B, W2, dinv, nullptr, A, N);
  k_pull<<<gPull, TB, 0, stream>>>(A, csr, offs, cursor, dinv, b2, B, N);

  // ---- head ----  out = h2 @ Wh + bh
  k_gemm<64, 40, RPW, false, true><<<gGemm, TB, 0, stream>>>(B, Wh, nullptr, bh, out, N);
}

// Round 5
// 390.006 us; speedup vs baseline: 3.6810x; 1.1460x over previous
//
#include <hip/hip_runtime.h>
#include <hip/hip_bf16.h>

// ---------------------------------------------------------------------------
// GCN: h1 = relu(gcnconv(x, W1, b1)); h2 = relu(gcnconv(h1, W2, b2));
//      out = h2 @ Wh + bh
// gcnconv(x,W,b)[d] = dinv[d] * ( sum_{e: src->d} hs[src] + hs[d] ) + b
//   where hs = (x@W) * dinv[row],  dinv = rsqrt(indeg + 1)
// CSR built per call. Fill is two-phase for write locality:
//   k_bin:  LDS split-sort edges into 128 dst-range buckets (coalesced out)
//   k_fill2: XCD-aligned consumption -> csr line writes stay in one L2.
// ---------------------------------------------------------------------------

#define BIN_B     128
#define BIN_SHIFT 10          // bucket = dst >> 10 (needs N <= 131072)
#define BIN_CHUNK 4096        // edges per k_bin block

__global__ __launch_bounds__(256) void k_zero(int* p, int n) {
  int i = blockIdx.x * blockDim.x + threadIdx.x;
  if (i < n) p[i] = 0;
}

__global__ __launch_bounds__(256) void k_count(const int* __restrict__ dst, int* cnt, int E) {
  int e = blockIdx.x * blockDim.x + threadIdx.x;
  if (e < E) atomicAdd(&cnt[dst[e]], 1);
}

__global__ __launch_bounds__(256) void k_dinv(const int* __restrict__ cnt, float* dinv, int n) {
  int i = blockIdx.x * blockDim.x + threadIdx.x;
  if (i < n) dinv[i] = rsqrtf((float)(cnt[i] + 1));   // +1 self-loop
}

// ---- 3-pass exclusive scan of cnt[n] -> offs[n]
__global__ __launch_bounds__(256) void k_scan1(const int* __restrict__ cnt,
                                               int* offs, int* bsum, int n) {
  __shared__ int sh[256];
  const int t = threadIdx.x;
  const int base = blockIdx.x * 1024 + t * 4;
  int v0 = 0, v1 = 0, v2 = 0, v3 = 0;
  if (base + 0 < n) v0 = cnt[base + 0];
  if (base + 1 < n) v1 = cnt[base + 1];
  if (base + 2 < n) v2 = cnt[base + 2];
  if (base + 3 < n) v3 = cnt[base + 3];
  const int s = v0 + v1 + v2 + v3;
  sh[t] = s;
  __syncthreads();
  for (int d = 1; d < 256; d <<= 1) {
    int x = (t >= d) ? sh[t - d] : 0;
    __syncthreads();
    sh[t] += x;
    __syncthreads();
  }
  int o = sh[t] - s;
  if (t == 255) bsum[blockIdx.x] = sh[255];
  if (base + 0 < n) { offs[base + 0] = o; o += v0; }
  if (base + 1 < n) { offs[base + 1] = o; o += v1; }
  if (base + 2 < n) { offs[base + 2] = o; o += v2; }
  if (base + 3 < n) { offs[base + 3] = o; o += v3; }
}

__global__ __launch_bounds__(256) void k_scan2(int* bsum, int nb) {
  __shared__ int sh[256];
  const int t = threadIdx.x;
  int v = (t < nb) ? bsum[t] : 0;
  sh[t] = v;
  __syncthreads();
  for (int d = 1; d < 256; d <<= 1) {
    int x = (t >= d) ? sh[t - d] : 0;
    __syncthreads();
    sh[t] += x;
    __syncthreads();
  }
  if (t < nb) bsum[t] = sh[t] - v;
}

__global__ __launch_bounds__(256) void k_scan3(int* offs, const int* __restrict__ bsum,
                                               int* cursor, int n) {
  int i = blockIdx.x * blockDim.x + threadIdx.x;
  if (i < n) {
    int o = offs[i] + bsum[i >> 10];
    offs[i] = o;
    cursor[i] = o;
  }
}

// bucket base offsets boff[0..BIN_B] and bin-phase cursors gcur[0..BIN_B)
__global__ __launch_bounds__(256) void k_bases(const int* __restrict__ offs,
                                               int* boff, int* gcur, int n, int E) {
  int t = threadIdx.x;
  if (t <= BIN_B) {
    int v = ((t << BIN_SHIFT) < n) ? offs[t << BIN_SHIFT] : E;
    boff[t] = v;
    if (t < BIN_B) gcur[t] = v;
  }
}

// Phase 1: split edges into BIN_B buckets by dst>>BIN_SHIFT.
// Output: binned[] packed (src<<BIN_SHIFT)|(dst & (2^BIN_SHIFT-1)), bucket
// regions identical to csr's bucket regions. Coalesced drain via LDS stage.
__global__ __launch_bounds__(256) void k_bin(
    const int* __restrict__ src, const int* __restrict__ dst,
    int* gcur, int* __restrict__ binned, int E)
{
  __shared__ int  hist[BIN_B];
  __shared__ int  excl[BIN_B];
  __shared__ int  lcur[BIN_B];
  __shared__ int  gbase[BIN_B];
  __shared__ int2 stage[BIN_CHUNK];

  const int t = threadIdx.x;
  const int base = blockIdx.x * BIN_CHUNK;
  const int m = min(BIN_CHUNK, E - base);

  int2 pr[BIN_CHUNK / 256];
  int nmine = 0;
  #pragma unroll
  for (int i = 0; i < BIN_CHUNK / 256; ++i) {
    int idx = t + 256 * i;
    if (idx < m) {
      pr[i].x = src[base + idx];
      pr[i].y = dst[base + idx];
      nmine = i + 1;
    }
  }

  if (t < BIN_B) hist[t] = 0;
  __syncthreads();
  #pragma unroll
  for (int i = 0; i < BIN_CHUNK / 256; ++i)
    if (i < nmine) atomicAdd(&hist[pr[i].y >> BIN_SHIFT], 1);
  __syncthreads();

  const int mycnt = (t < BIN_B) ? hist[t] : 0;
  for (int d = 1; d < BIN_B; d <<= 1) {
    int v = (t < BIN_B && t >= d) ? hist[t - d] : 0;
    __syncthreads();
    if (t < BIN_B) hist[t] += v;
    __syncthreads();
  }
  if (t < BIN_B) {
    int e = hist[t] - mycnt;       // exclusive prefix within block
    excl[t] = e;
    lcur[t] = e;
    gbase[t] = mycnt ? atomicAdd(&gcur[t], mycnt) : 0;
  }
  __syncthreads();

  #pragma unroll
  for (int i = 0; i < BIN_CHUNK / 256; ++i)
    if (i < nmine) {
      int b = pr[i].y >> BIN_SHIFT;
      int p = atomicAdd(&lcur[b], 1);
      stage[p] = pr[i];
    }
  __syncthreads();

  for (int i = t; i < m; i += 256) {
    int2 pp = stage[i];
    int b = pp.y >> BIN_SHIFT;
    binned[gbase[b] + (i - excl[b])] =
        (pp.x << BIN_SHIFT) | (pp.y & ((1 << BIN_SHIFT) - 1));
  }
}

// Phase 2: consume binned edges; bucket b handled ONLY by blocks with
// blockIdx%8 == b%8 (XCD-aligned) so csr line writes stay in one L2.
__global__ __launch_bounds__(256) void k_fill2(
    const int* __restrict__ binned, const int* __restrict__ boff,
    int* cursor, int* csr)
{
  const int xcd = blockIdx.x & 7;
  const int tt  = blockIdx.x >> 3;
  const int b   = xcd + 8 * (tt & 15);       // [0, 128)
  const int c   = tt >> 4;                   // chunk 0..7
  const int bstart = boff[b];
  const int bend   = boff[b + 1];
  const int tid_in = c * 256 + threadIdx.x;  // [0, 2048)
  for (int i = bstart + tid_in; i < bend; i += 2048) {
    int v = binned[i];
    int d = (b << BIN_SHIFT) + (v & ((1 << BIN_SHIFT) - 1));
    int s = v >> BIN_SHIFT;
    int slot = atomicAdd(&cursor[d], 1);
    csr[slot] = s;
  }
}

// Fallback single-pass fill (used only if N > 2^(31-BIN_SHIFT... pack) range)
__global__ __launch_bounds__(256) void k_fill(const int* __restrict__ src,
                                              const int* __restrict__ dst,
                                              int* cursor, int* csr, int E) {
  int e = blockIdx.x * blockDim.x + threadIdx.x;
  if (e < E) {
    int p = atomicAdd(&cursor[dst[e]], 1);
    csr[p] = src[e];
  }
}

// Y[row][j] = (sum_k X[row][k] * W[k][j]) [*dinv[row]] [+bias[j]]
// WT in LDS [NOUT][K+4] (b128 reads, bank-even); 4 uniform rows/wave via
// readfirstlane -> s_load; RPW rows sequential per wave.
template<int K, int NOUT, int RPW, bool SCALE, bool BIAS>
__global__ __launch_bounds__(256) void k_gemm(
    const float* __restrict__ X, const float* __restrict__ W,
    const float* __restrict__ dinv, const float* __restrict__ bias,
    float* __restrict__ Y, int nrows)
{
  constexpr int LDW = K + 4;
  __shared__ float WT[NOUT * LDW];
  for (int idx = threadIdx.x; idx < K * NOUT; idx += 256) {
    int k = idx / NOUT, j = idx - k * NOUT;
    WT[j * LDW + k] = W[idx];
  }
  __syncthreads();

  const int wid  = threadIdx.x >> 6;
  const int lane = threadIdx.x & 63;
  const int j    = (NOUT < 64 && lane >= NOUT) ? (NOUT - 1) : lane;
  const float bj = BIAS ? bias[j] : 0.f;
  const float* wrow = &WT[j * LDW];

  const int rowbase = (blockIdx.x * 4 + wid) * RPW;

  #pragma unroll 1
  for (int rr = 0; rr < RPW; rr += 4) {
    const int r0 = rowbase + rr;
    int c0 = (r0 + 0 < nrows) ? r0 + 0 : nrows - 1;
    int c1 = (r0 + 1 < nrows) ? r0 + 1 : nrows - 1;
    int c2 = (r0 + 2 < nrows) ? r0 + 2 : nrows - 1;
    int c3 = (r0 + 3 < nrows) ? r0 + 3 : nrows - 1;
    c0 = __builtin_amdgcn_readfirstlane(c0);
    c1 = __builtin_amdgcn_readfirstlane(c1);
    c2 = __builtin_amdgcn_readfirstlane(c2);
    c3 = __builtin_amdgcn_readfirstlane(c3);
    const float* x0 = X + (size_t)c0 * K;
    const float* x1 = X + (size_t)c1 * K;
    const float* x2 = X + (size_t)c2 * K;
    const float* x3 = X + (size_t)c3 * K;

    float a0 = 0.f, a1 = 0.f, a2 = 0.f, a3 = 0.f;
    #pragma unroll 4
    for (int k = 0; k < K; k += 4) {
      const float4 wv = *(const float4*)(wrow + k);
      const float4 p0 = *(const float4*)(x0 + k);
      const float4 p1 = *(const float4*)(x1 + k);
      const float4 p2 = *(const float4*)(x2 + k);
      const float4 p3 = *(const float4*)(x3 + k);
      a0 = fmaf(p0.x, wv.x, a0); a0 = fmaf(p0.y, wv.y, a0);
      a0 = fmaf(p0.z, wv.z, a0); a0 = fmaf(p0.w, wv.w, a0);
      a1 = fmaf(p1.x, wv.x, a1); a1 = fmaf(p1.y, wv.y, a1);
      a1 = fmaf(p1.z, wv.z, a1); a1 = fmaf(p1.w, wv.w, a1);
      a2 = fmaf(p2.x, wv.x, a2); a2 = fmaf(p2.y, wv.y, a2);
      a2 = fmaf(p2.z, wv.z, a2); a2 = fmaf(p2.w, wv.w, a2);
      a3 = fmaf(p3.x, wv.x, a3); a3 = fmaf(p3.y, wv.y, a3);
      a3 = fmaf(p3.z, wv.z, a3); a3 = fmaf(p3.w, wv.w, a3);
    }

    float accs[4] = {a0, a1, a2, a3};
    #pragma unroll
    for (int r = 0; r < 4; ++r) {
      const int row = r0 + r;
      if (row < nrows && lane < NOUT) {
        float v = accs[r];
        if constexpr (SCALE) v *= dinv[row];
        if constexpr (BIAS)  v += bj;
        Y[(size_t)row * NOUT + lane] = v;
      }
    }
  }
}

// Pull-aggregate + fused epilogue. One wave per node, lane = feature.
__global__ __launch_bounds__(256) void k_pull(
    const float* __restrict__ hs, const int* __restrict__ csr,
    const int* __restrict__ offs, const int* __restrict__ endo,
    const float* __restrict__ dinv, const float* __restrict__ bias,
    float* __restrict__ out, int n)
{
  const int node = blockIdx.x * 4 + (threadIdx.x >> 6);
  if (node >= n) return;
  const int lane = threadIdx.x & 63;

  const int beg = offs[node];
  const int m   = endo[node] - beg;

  float acc0 = hs[(size_t)node * 64 + lane];   // self term
  float acc1 = 0.f;

  for (int base = 0; base < m; base += 64) {
    const int kk = (m - base < 64) ? (m - base) : 64;
    const int myidx = (base + lane < m) ? csr[beg + base + lane] : 0;
    int i = 0;
    for (; i + 4 <= kk; i += 4) {
      int s0 = __shfl(myidx, i + 0);
      int s1 = __shfl(myidx, i + 1);
      int s2 = __shfl(myidx, i + 2);
      int s3 = __shfl(myidx, i + 3);
      float v0 = hs[(size_t)s0 * 64 + lane];
      float v1 = hs[(size_t)s1 * 64 + lane];
      float v2 = hs[(size_t)s2 * 64 + lane];
      float v3 = hs[(size_t)s3 * 64 + lane];
      acc0 += v0; acc1 += v1; acc0 += v2; acc1 += v3;
    }
    for (; i < kk; ++i) {
      int s = __shfl(myidx, i);
      acc0 += hs[(size_t)s * 64 + lane];
    }
  }
  float v = fmaf(dinv[node], acc0 + acc1, bias[lane]);
  out[(size_t)node * 64 + lane] = fmaxf(v, 0.f);
}

extern "C" void kernel_launch(void* const* d_in, const int* in_sizes, int n_in,
                              void* d_out, int out_size, void* d_ws, size_t ws_size,
                              hipStream_t stream) {
  const float* x  = (const float*)d_in[0];
  const int*   ei = (const int*)d_in[1];
  const float* W1 = (const float*)d_in[2];
  const float* b1 = (const float*)d_in[3];
  const float* W2 = (const float*)d_in[4];
  const float* b2 = (const float*)d_in[5];
  const float* Wh = (const float*)d_in[6];
  const float* bh = (const float*)d_in[7];
  float* out = (float*)d_out;

  const int N = in_sizes[0] / 128;
  const int E = in_sizes[1] / 2;
  const int* src = ei;
  const int* dst = ei + E;

  auto align_up = [](size_t v, size_t a) { return (v + a - 1) & ~(a - 1); };
  char* ws = (char*)d_ws;
  size_t off = 0;
  int*   cnt    = (int*)(ws + off);   off = align_up(off + (size_t)N * 4, 256);
  float* dinv   = (float*)(ws + off); off = align_up(off + (size_t)N * 4, 256);
  int*   offs   = (int*)(ws + off);   off = align_up(off + (size_t)N * 4, 256);
  int*   cursor = (int*)(ws + off);   off = align_up(off + (size_t)N * 4, 256);
  int*   bsum   = (int*)(ws + off);   off = align_up(off + 256 * 4, 256);
  int*   boff   = (int*)(ws + off);   off = align_up(off + (BIN_B + 1) * 4, 256);
  int*   gcur   = (int*)(ws + off);   off = align_up(off + BIN_B * 4, 256);
  int*   csr    = (int*)(ws + off);   off = align_up(off + (size_t)E * 4, 256);
  int*   binned = (int*)(ws + off);   off = align_up(off + (size_t)E * 4, 256);
  float* A      = (float*)(ws + off); off = align_up(off + (size_t)N * 64 * 4, 256);
  float* B      = (float*)(ws + off); off = align_up(off + (size_t)N * 64 * 4, 256);
  (void)ws_size;

  const int TB = 256;
  const int gN = (N + TB - 1) / TB;
  const int gE = (E + TB - 1) / TB;
  const int nb = (N + 1023) / 1024;
  constexpr int RPW = 16;
  const int gGemm = (N + 4 * RPW - 1) / (4 * RPW);
  const int gPull = (N + 3) / 4;
  const int gBin  = (E + BIN_CHUNK - 1) / BIN_CHUNK;

  // ---- degree + scan ----
  k_zero <<<gN, TB, 0, stream>>>(cnt, N);
  k_count<<<gE, TB, 0, stream>>>(dst, cnt, E);
  k_dinv <<<gN, TB, 0, stream>>>(cnt, dinv, N);
  k_scan1<<<nb, TB, 0, stream>>>(cnt, offs, bsum, N);
  k_scan2<<<1,  TB, 0, stream>>>(bsum, nb);
  k_scan3<<<gN, TB, 0, stream>>>(offs, bsum, cursor, N);

  // ---- CSR fill ----
  if (N <= (1 << (31 - BIN_SHIFT)) && N <= (BIN_B << BIN_SHIFT)) {
    k_bases<<<1, TB, 0, stream>>>(offs, boff, gcur, N, E);
    k_bin  <<<gBin, TB, 0, stream>>>(src, dst, gcur, binned, E);
    k_fill2<<<8 * 16 * 8, TB, 0, stream>>>(binned, boff, cursor, csr);
  } else {
    k_fill <<<gE, TB, 0, stream>>>(src, dst, cursor, csr, E);
  }

  // ---- layer 1 ----  A = hs1 = (x@W1)*dinv ; B = h1
  k_gemm<128, 64, RPW, true, false><<<gGemm, TB, 0, stream>>>(x, W1, dinv, nullptr, A, N);
  k_pull<<<gPull, TB, 0, stream>>>(A, csr, offs, cursor, dinv, b1, B, N);

  // ---- layer 2 ----  A = hs2 = (h1@W2)*dinv ; B = h2
  k_gemm<64, 64, RPW, true, false><<<gGemm, TB, 0, stream>>>(B, W2, dinv, nullptr, A, N);
  k_pull<<<gPull, TB, 0, stream>>>(A, csr, offs, cursor, dinv, b2, B, N);

  // ---- head ----  out = h2 @ Wh + bh
  k_gemm<64, 40, RPW, false, true><<<gGemm, TB, 0, stream>>>(B, Wh, nullptr, bh, out, N);
}